// Round 9
// baseline (4485.545 us; speedup 1.0000x reference)
//
#include <hip/hip_runtime.h>

#define IN_F 4096
#define OUT_F 4096
#define RANK 16
#define NTOK 8192
#define KP 4160            // IN_F + 16 lora cols + 48 zero pad = 130 * 32
#define BK2 32
#define NT (KP / BK2)      // 130
#define BM 256
#define BN 256

typedef __bf16 bf16x8 __attribute__((ext_vector_type(8)));
typedef float f32x4 __attribute__((ext_vector_type(4)));

__device__ __forceinline__ unsigned short f2bf(float f) {
  unsigned int u = __float_as_uint(f);
  u += 0x7fffu + ((u >> 16) & 1u);   // round-to-nearest-even
  return (unsigned short)(u >> 16);
}

__device__ __forceinline__ void async_ld16(const void* g, void* l) {
  __builtin_amdgcn_global_load_lds(
      (const __attribute__((address_space(1))) unsigned int*)g,
      (__attribute__((address_space(3))) unsigned int*)l, 16, 0, 0);
}

__device__ const float NF4_TAB[16] = {
    -1.0f, -0.6961928009986877f, -0.5250730514526367f, -0.39491748809814453f,
    -0.28444138169288635f, -0.18477343022823334f, -0.09105003625154495f, 0.0f,
    0.07958029955625534f, 0.16093020141124725f, 0.24611230194568634f,
    0.33791524171829224f, 0.44070982933044434f, 0.5626170039176941f,
    0.7229568362236023f, 1.0f};

// ---------------- K1: x -> bf16 A', fused lora_down t = x @ Ld^T ----------------
__global__ __launch_bounds__(256) void k_prep_a(
    const float* __restrict__ x, const float* __restrict__ ldw,
    unsigned short* __restrict__ Ap) {
  const int tid = threadIdx.x;
  const int lane = tid & 63;
  const int w = tid >> 6;
  const int m0 = blockIdx.x * 4;

  float acc[4][4];
#pragma unroll
  for (int i = 0; i < 4; ++i)
#pragma unroll
    for (int rl = 0; rl < 4; ++rl) acc[i][rl] = 0.f;

  for (int c = 0; c < 16; ++c) {
    const int k0 = (c * 64 + lane) * 4;
    float4 xv[4];
#pragma unroll
    for (int i = 0; i < 4; ++i) {
      xv[i] = *(const float4*)&x[(size_t)(m0 + i) * IN_F + k0];
      if (w == i) {
        ushort4 s;
        s.x = f2bf(xv[i].x); s.y = f2bf(xv[i].y);
        s.z = f2bf(xv[i].z); s.w = f2bf(xv[i].w);
        *(ushort4*)&Ap[(size_t)(m0 + i) * KP + k0] = s;
      }
    }
#pragma unroll
    for (int rl = 0; rl < 4; ++rl) {
      float4 lv = *(const float4*)&ldw[(size_t)(w * 4 + rl) * IN_F + k0];
#pragma unroll
      for (int i = 0; i < 4; ++i)
        acc[i][rl] += xv[i].x * lv.x + xv[i].y * lv.y + xv[i].z * lv.z +
                      xv[i].w * lv.w;
    }
  }
#pragma unroll
  for (int i = 0; i < 4; ++i)
#pragma unroll
    for (int rl = 0; rl < 4; ++rl) {
      float v = acc[i][rl];
#pragma unroll
      for (int m = 1; m < 64; m <<= 1) v += __shfl_xor(v, m, 64);
      acc[i][rl] = v;
    }
  __shared__ float red[4][16];
  if (lane == 0) {
#pragma unroll
    for (int i = 0; i < 4; ++i)
#pragma unroll
      for (int rl = 0; rl < 4; ++rl) red[i][w * 4 + rl] = acc[i][rl];
  }
  __syncthreads();
  if (tid < 64) {
    Ap[(size_t)(m0 + (tid >> 4)) * KP + IN_F + (tid & 15)] =
        f2bf(red[tid >> 4][tid & 15]);
  } else {
    const int t2 = tid - 64;
    if (t2 < 192)
      Ap[(size_t)(m0 + t2 / 48) * KP + IN_F + 16 + (t2 % 48)] = 0;
  }
}

// ---------------- K2: NF4 dequant -> bf16 B', append Lu*(alpha/r) ----------------
__global__ __launch_bounds__(256) void k_prep_b(
    const int* __restrict__ q, const float* __restrict__ amax,
    const float* __restrict__ luw, const float* __restrict__ alpha,
    unsigned short* __restrict__ Bp) {
  __shared__ float tab[16];
  const int tid = threadIdx.x;
  const int n = blockIdx.x;
  if (tid < 16) tab[tid] = NF4_TAB[tid];
  __syncthreads();
#pragma unroll
  for (int c = 0; c < 4; ++c) {
    const int k0 = (tid + 256 * c) * 4;
    int4 qv = *(const int4*)&q[(size_t)n * IN_F + k0];
    float am = amax[n * (IN_F / 64) + (k0 >> 6)];
    ushort4 s;
    s.x = f2bf(tab[qv.x] * am);
    s.y = f2bf(tab[qv.y] * am);
    s.z = f2bf(tab[qv.z] * am);
    s.w = f2bf(tab[qv.w] * am);
    *(ushort4*)&Bp[(size_t)n * KP + k0] = s;
  }
  if (tid < RANK) {
    float sc = alpha[0] * (1.0f / RANK);
    Bp[(size_t)n * KP + IN_F + tid] = f2bf(luw[n * RANK + tid] * sc);
  } else if (tid < 64) {
    Bp[(size_t)n * KP + IN_F + tid] = 0;
  }
}

// ---------------- K3: 256x256 bf16 GEMM, BK=32, 64KB LDS, 2 blocks/CU ----------
// Occupancy-driven overlap (m97/m114 mechanism): two independent blocks per CU
// fill each other's barrier stalls. Per K-step (BK=32): 32 MFMA/wave in 2
// phases; 12 ds_reads/wave (one step ahead: tile t+1 read at ph1(t) tail,
// AFTER the vmcnt+barrier that retires t+1); stage tile t+2 (4 loads/thread-
// block-wide) at ph1 top; counted vmcnt(4) keeps t+2 in flight. Sync points
// bunched mid-step: ph1-tail -> ph0(t+1) is a sync-free run (28 MFMA + 12
// reads). Swizzle (BK=32): phys_slot = slot ^ ((row>>1)&3), applied on
// staging source and ds_read addr (both-sides rule); 2-way max = free.
// Register ping-pong a1/b via manual 2-step unroll (no runtime indexing).
__global__ __launch_bounds__(512, 4) void k_gemm(
    const unsigned short* __restrict__ Ap, const unsigned short* __restrict__ Bp,
    const float* __restrict__ bias, float* __restrict__ out) {
  __shared__ unsigned short lds[32768];  // 64 KiB: buf[2] x {A[256][32], B[256][32]}
  const int tid = threadIdx.x;
  const int lane = tid & 63;
  const int w = tid >> 6;
  const int wr = w >> 2;       // 0..1
  const int wc = w & 3;        // 0..3

  // T1: XCD swizzle, grid 512 (divisible by 8)
  const int flat = blockIdx.x;
  const int swz = (flat & 7) * 64 + (flat >> 3);
  const int m0 = (swz >> 4) * BM;
  const int n0 = (swz & 15) * BN;

  // staging: thread covers row w*16 + (lane>>2), 16B slot (lane&3), all 4
  // half-tiles. Source slot pre-swizzled: (lane&3) ^ ((row>>1)&3) = ^(lane>>3)&3.
  const int srow = lane >> 2;                               // 0..15
  const int sslot = (((lane & 3) ^ ((lane >> 3) & 3)) << 3);  // bf16 elems
  const unsigned short* gA = Ap + (size_t)(m0 + (w << 4) + srow) * KP + sslot;
  const unsigned short* gB = Bp + (size_t)(n0 + (w << 4) + srow) * KP + sslot;
  unsigned short* const ldsw = lds + (w << 9);              // w*512 shorts

  // ds_read: row = lane&15, global slot = lane>>4, phys = g ^ ((lane>>1)&3)
  const int rdoff = ((lane & 15) << 5) + ((((lane >> 4) ^ ((lane >> 1) & 3))) << 3);

#define STAGE(tt, cond)                                                        \
  if (cond) {                                                                  \
    const int bo = ((tt)&1) << 14;                                             \
    async_ld16(gA + (size_t)(tt)*BK2, ldsw + bo);                              \
    async_ld16(gA + (size_t)128 * KP + (size_t)(tt)*BK2, ldsw + bo + 4096);    \
    async_ld16(gB + (size_t)(tt)*BK2, ldsw + bo + 8192);                       \
    async_ld16(gB + (size_t)128 * KP + (size_t)(tt)*BK2, ldsw + bo + 12288);   \
  }

#define LDA(bsel, mi)                                                          \
  (*(const bf16x8*)&lds[((bsel) << 14) + (wr << 12) + ((mi) << 9) + rdoff])
#define LDB(bsel, nj)                                                          \
  (*(const bf16x8*)&lds[((bsel) << 14) + 8192 + (wc << 11) + ((nj) << 9) + rdoff])

#define MFMA(a, b, c) __builtin_amdgcn_mfma_f32_16x16x32_bf16((a), (b), (c), 0, 0, 0)
#define SG(mask, n) __builtin_amdgcn_sched_group_barrier((mask), (n), 0)
#define BAR() asm volatile("s_barrier" ::: "memory")

  // ---- prologue: stage tiles 0,1; land tile0 (keep tile1 flying); read t0 ----
  STAGE(0, true)
  STAGE(1, true)
  asm volatile("s_waitcnt vmcnt(4)" ::: "memory");
  BAR();

  f32x4 acc[8][4] = {};
  bf16x8 a0[4], a1A[4], a1B[4], bA[4], bB[4];

#pragma unroll
  for (int g = 0; g < 4; ++g) bA[g] = LDB(0, g);
#pragma unroll
  for (int f = 0; f < 4; ++f) a0[f] = LDA(0, f);
#pragma unroll
  for (int f = 0; f < 4; ++f) a1A[f] = LDA(0, 4 + f);

  for (int t = 0; t < NT; t += 2) {
    // ================= even step: bsel=0, cur = {a1A, bA} =================
    // ph0: pure MFMA (a0 x bA)
    __builtin_amdgcn_s_setprio(1);
#pragma unroll
    for (int f = 0; f < 4; ++f)
#pragma unroll
      for (int g = 0; g < 4; ++g) acc[f][g] = MFMA(a0[f], bA[g], acc[f][g]);
    __builtin_amdgcn_s_setprio(0);
    BAR();  // #1: separates buf0 reads (issued ph1(t-1)) from stage below
    // ph1: stage t+2 -> buf0; retire t+1; then reads of t+1 (buf1) || MFMA
    STAGE(t + 2, t + 2 < NT)
    if (t + 2 < NT) {
      asm volatile("s_waitcnt vmcnt(4)" ::: "memory");
    } else {
      asm volatile("s_waitcnt vmcnt(0)" ::: "memory");
    }
    BAR();  // #2: t+1 landed for all waves
    __builtin_amdgcn_sched_barrier(0);
    if (t + 1 < NT) {
#pragma unroll
      for (int g = 0; g < 4; ++g) bB[g] = LDB(1, g);
#pragma unroll
      for (int f = 0; f < 4; ++f) a0[f] = LDA(1, f);
#pragma unroll
      for (int f = 0; f < 4; ++f) a1B[f] = LDA(1, 4 + f);
    }
    __builtin_amdgcn_s_setprio(1);
#pragma unroll
    for (int f = 0; f < 4; ++f)
#pragma unroll
      for (int g = 0; g < 4; ++g)
        acc[4 + f][g] = MFMA(a1A[f], bA[g], acc[4 + f][g]);
    __builtin_amdgcn_s_setprio(0);
#pragma unroll
    for (int i = 0; i < 4; ++i) { SG(0x100, 3); SG(0x8, 4); }
    // ================= odd step: bsel=1, cur = {a1B, bB} =================
    if (t + 1 < NT) {
      // ph0: pure MFMA (a0 x bB)
      __builtin_amdgcn_s_setprio(1);
#pragma unroll
      for (int f = 0; f < 4; ++f)
#pragma unroll
        for (int g = 0; g < 4; ++g) acc[f][g] = MFMA(a0[f], bB[g], acc[f][g]);
      __builtin_amdgcn_s_setprio(0);
      BAR();  // #1
      // ph1: stage t+3 -> buf1; retire t+2; reads of t+2 (buf0) || MFMA
      STAGE(t + 3, t + 3 < NT)
      if (t + 3 < NT) {
        asm volatile("s_waitcnt vmcnt(4)" ::: "memory");
      } else {
        asm volatile("s_waitcnt vmcnt(0)" ::: "memory");
      }
      BAR();  // #2
      __builtin_amdgcn_sched_barrier(0);
      if (t + 2 < NT) {
#pragma unroll
        for (int g = 0; g < 4; ++g) bA[g] = LDB(0, g);
#pragma unroll
        for (int f = 0; f < 4; ++f) a0[f] = LDA(0, f);
#pragma unroll
        for (int f = 0; f < 4; ++f) a1A[f] = LDA(0, 4 + f);
      }
      __builtin_amdgcn_s_setprio(1);
#pragma unroll
      for (int f = 0; f < 4; ++f)
#pragma unroll
        for (int g = 0; g < 4; ++g)
          acc[4 + f][g] = MFMA(a1B[f], bB[g], acc[4 + f][g]);
      __builtin_amdgcn_s_setprio(0);
#pragma unroll
      for (int i = 0; i < 4; ++i) { SG(0x100, 3); SG(0x8, 4); }
    }
  }

  // ---- epilogue: bias + f32 store (C/D: col = lane&15, row = (lane>>4)*4+e) ----
  const int colL = lane & 15;
  const int rowG = lane >> 4;
#pragma unroll
  for (int nj = 0; nj < 4; ++nj) {
    const int n = n0 + wc * 64 + nj * 16 + colL;
    const float bv = bias[n];
#pragma unroll
    for (int mi = 0; mi < 8; ++mi) {
      const int mb = m0 + wr * 128 + mi * 16 + rowG * 4;
#pragma unroll
      for (int e = 0; e < 4; ++e)
        out[(size_t)(mb + e) * OUT_F + n] = acc[mi][nj][e] + bv;
    }
  }
#undef STAGE
#undef LDA
#undef LDB
#undef MFMA
#undef SG
#undef BAR
}

extern "C" void kernel_launch(void* const* d_in, const int* in_sizes, int n_in,
                              void* d_out, int out_size, void* d_ws, size_t ws_size,
                              hipStream_t stream) {
  (void)in_sizes; (void)n_in; (void)out_size; (void)ws_size;
  const float* x     = (const float*)d_in[0];
  const float* amax  = (const float*)d_in[1];
  const float* bias  = (const float*)d_in[2];
  const float* ldw   = (const float*)d_in[3];
  const float* luw   = (const float*)d_in[4];
  const float* alpha = (const float*)d_in[5];
  const int*   q     = (const int*)d_in[6];
  float* out = (float*)d_out;

  unsigned short* Ap = (unsigned short*)d_ws;                 // [NTOK][KP] bf16
  unsigned short* Bp = Ap + (size_t)NTOK * KP;                // [OUT_F][KP] bf16

  k_prep_a<<<NTOK / 4, 256, 0, stream>>>(x, ldw, Ap);
  k_prep_b<<<OUT_F, 256, 0, stream>>>(q, amax, luw, alpha, Bp);
  k_gemm<<<512, 512, 0, stream>>>(Ap, Bp, bias, out);
}

// Round 10
// 410.112 us; speedup vs baseline: 10.9374x; 10.9374x over previous
//
#include <hip/hip_runtime.h>

#define IN_F 4096
#define OUT_F 4096
#define RANK 16
#define NTOK 8192
#define KP 4160            // IN_F + 16 lora cols + 48 zero pad = 65 * 64
#define BK 64
#define NT (KP / BK)       // 65
#define BM 256
#define BN 256

typedef __bf16 bf16x8 __attribute__((ext_vector_type(8)));
typedef float f32x4 __attribute__((ext_vector_type(4)));

__device__ __forceinline__ unsigned short f2bf(float f) {
  unsigned int u = __float_as_uint(f);
  u += 0x7fffu + ((u >> 16) & 1u);   // round-to-nearest-even
  return (unsigned short)(u >> 16);
}

__device__ __forceinline__ void async_ld16(const void* g, void* l) {
  __builtin_amdgcn_global_load_lds(
      (const __attribute__((address_space(1))) unsigned int*)g,
      (__attribute__((address_space(3))) unsigned int*)l, 16, 0, 0);
}

__device__ const float NF4_TAB[16] = {
    -1.0f, -0.6961928009986877f, -0.5250730514526367f, -0.39491748809814453f,
    -0.28444138169288635f, -0.18477343022823334f, -0.09105003625154495f, 0.0f,
    0.07958029955625534f, 0.16093020141124725f, 0.24611230194568634f,
    0.33791524171829224f, 0.44070982933044434f, 0.5626170039176941f,
    0.7229568362236023f, 1.0f};

// ---------------- K1: x -> bf16 A', fused lora_down t = x @ Ld^T ----------------
__global__ __launch_bounds__(256) void k_prep_a(
    const float* __restrict__ x, const float* __restrict__ ldw,
    unsigned short* __restrict__ Ap) {
  const int tid = threadIdx.x;
  const int lane = tid & 63;
  const int w = tid >> 6;
  const int m0 = blockIdx.x * 4;

  float acc[4][4];
#pragma unroll
  for (int i = 0; i < 4; ++i)
#pragma unroll
    for (int rl = 0; rl < 4; ++rl) acc[i][rl] = 0.f;

  for (int c = 0; c < 16; ++c) {
    const int k0 = (c * 64 + lane) * 4;
    float4 xv[4];
#pragma unroll
    for (int i = 0; i < 4; ++i) {
      xv[i] = *(const float4*)&x[(size_t)(m0 + i) * IN_F + k0];
      if (w == i) {
        ushort4 s;
        s.x = f2bf(xv[i].x); s.y = f2bf(xv[i].y);
        s.z = f2bf(xv[i].z); s.w = f2bf(xv[i].w);
        *(ushort4*)&Ap[(size_t)(m0 + i) * KP + k0] = s;
      }
    }
#pragma unroll
    for (int rl = 0; rl < 4; ++rl) {
      float4 lv = *(const float4*)&ldw[(size_t)(w * 4 + rl) * IN_F + k0];
#pragma unroll
      for (int i = 0; i < 4; ++i)
        acc[i][rl] += xv[i].x * lv.x + xv[i].y * lv.y + xv[i].z * lv.z +
                      xv[i].w * lv.w;
    }
  }
#pragma unroll
  for (int i = 0; i < 4; ++i)
#pragma unroll
    for (int rl = 0; rl < 4; ++rl) {
      float v = acc[i][rl];
#pragma unroll
      for (int m = 1; m < 64; m <<= 1) v += __shfl_xor(v, m, 64);
      acc[i][rl] = v;
    }
  __shared__ float red[4][16];
  if (lane == 0) {
#pragma unroll
    for (int i = 0; i < 4; ++i)
#pragma unroll
      for (int rl = 0; rl < 4; ++rl) red[i][w * 4 + rl] = acc[i][rl];
  }
  __syncthreads();
  if (tid < 64) {
    Ap[(size_t)(m0 + (tid >> 4)) * KP + IN_F + (tid & 15)] =
        f2bf(red[tid >> 4][tid & 15]);
  } else {
    const int t2 = tid - 64;
    if (t2 < 192)
      Ap[(size_t)(m0 + t2 / 48) * KP + IN_F + 16 + (t2 % 48)] = 0;
  }
}

// ---------------- K2: NF4 dequant -> bf16 B', append Lu*(alpha/r) ----------------
__global__ __launch_bounds__(256) void k_prep_b(
    const int* __restrict__ q, const float* __restrict__ amax,
    const float* __restrict__ luw, const float* __restrict__ alpha,
    unsigned short* __restrict__ Bp) {
  __shared__ float tab[16];
  const int tid = threadIdx.x;
  const int n = blockIdx.x;
  if (tid < 16) tab[tid] = NF4_TAB[tid];
  __syncthreads();
#pragma unroll
  for (int c = 0; c < 4; ++c) {
    const int k0 = (tid + 256 * c) * 4;
    int4 qv = *(const int4*)&q[(size_t)n * IN_F + k0];
    float am = amax[n * (IN_F / 64) + (k0 >> 6)];
    ushort4 s;
    s.x = f2bf(tab[qv.x] * am);
    s.y = f2bf(tab[qv.y] * am);
    s.z = f2bf(tab[qv.z] * am);
    s.w = f2bf(tab[qv.w] * am);
    *(ushort4*)&Bp[(size_t)n * KP + k0] = s;
  }
  if (tid < RANK) {
    float sc = alpha[0] * (1.0f / RANK);
    Bp[(size_t)n * KP + IN_F + tid] = f2bf(luw[n * RANK + tid] * sc);
  } else if (tid < 64) {
    Bp[(size_t)n * KP + IN_F + tid] = 0;
  }
}

// ---------------- K3: 256x256 bf16 GEMM, balanced read schedule ----------------
// R8 skeleton with the ph3 read-bunch (12 reads against 16 MFMA while ph2's
// 16 MFMA ran with idle LDS port) split: gate (vmcnt+barrier) moves to MID-ph2,
// and 8 of the 12 tile-(t+1) reads move to ph2-post-gate interleaved with the
// remaining 8 MFMA. Per-wave read distribution per tile: ph0: 8 (a0[2,3](t) +
// b1(t)), ph1: 8 (a1(t)), ph2b: 8 (b0(t+1) + a0[0,1](t+1)), ph3: 0.
// b0 double-set (b0A/b0B) ping-pong via manual 2-step unroll (b0(t) stays
// live through ph3 while b0(t+1) arrives at ph2b). Gate accounting as R8:
// vmcnt(4) retires A(t+1)+B(t+1), keeps B(t+2) in flight. 2 barriers/tile.
__global__ __launch_bounds__(512, 1) void k_gemm(
    const unsigned short* __restrict__ Ap, const unsigned short* __restrict__ Bp,
    const float* __restrict__ bias, float* __restrict__ out) {
  __shared__ unsigned short lds[65536];  // 128 KiB
  const int tid = threadIdx.x;
  const int lane = tid & 63;
  const int w = tid >> 6;
  const int wr = w >> 2;       // 0..1
  const int wc = w & 3;        // 0..3

  // T1: XCD swizzle, 1-D grid of 512 (divisible by 8)
  const int flat = blockIdx.x;
  const int swz = (flat & 7) * 64 + (flat >> 3);
  const int m0 = (swz >> 4) * BM;
  const int n0 = (swz & 15) * BN;

  const int srow = lane >> 3;
  const int scol = (((lane & 7) ^ srow) << 3);
  const unsigned short* gA = Ap + (size_t)(m0 + (w << 4) + srow) * KP + scol;
  const unsigned short* gB = Bp + (size_t)(n0 + (w << 4) + srow) * KP + scol;
  unsigned short* const ldsw = lds + (w << 10);

  const int rdoff = ((lane & 15) << 6) + (((lane >> 4) ^ (lane & 7)) << 3);

#define STAGE2(tt, ht, cond)                                                   \
  if (cond) {                                                                  \
    const unsigned short* s_ =                                                 \
        ((ht) < 2 ? gA + (size_t)((ht) << 7) * KP                              \
                  : gB + (size_t)(((ht)-2) << 7) * KP) + (size_t)(tt)*BK;      \
    unsigned short* d_ = ldsw + ((((tt)&1) << 15) + ((ht) << 13));             \
    async_ld16(s_, d_);                                                        \
    async_ld16(s_ + (size_t)8 * KP, d_ + 512);                                 \
  }

#define LDA(bsel, mh, f, kc)                                                   \
  (*(const bf16x8*)&lds[((bsel) << 15) + (wr << 13) +                          \
                        (((mh)*64 + (f)*16) << 6) + (((kc) << 5) ^ rdoff)])
#define LDB(bsel, nh, g, kc)                                                   \
  (*(const bf16x8*)&lds[((bsel) << 15) + ((2 + (wc >> 1)) << 13) +             \
                        ((((wc & 1) * 64) + (nh)*32 + (g)*16) << 6) +          \
                        (((kc) << 5) ^ rdoff)])

#define MFMA(a, b, c) __builtin_amdgcn_mfma_f32_16x16x32_bf16((a), (b), (c), 0, 0, 0)
#define SG(mask, n) __builtin_amdgcn_sched_group_barrier((mask), (n), 0)
#define BAR() __builtin_amdgcn_s_barrier()

  // ---- prologue: B(0),A(0),B(1),A(1) FIFO; land tile0; initial frags ----
  STAGE2(0, 2, true) STAGE2(0, 3, true) STAGE2(0, 0, true) STAGE2(0, 1, true)
  STAGE2(1, 2, true) STAGE2(1, 3, true) STAGE2(1, 0, true) STAGE2(1, 1, true)
  asm volatile("s_waitcnt vmcnt(8)" ::: "memory");   // tile0 landed
  BAR();

  f32x4 acc[8][4] = {};
  bf16x8 a0[4][2], a1[4][2], b1[2][2], b0A[2][2], b0B[2][2];

  // initial: b0A(0) + a0[0,1](0)  (plays the role of ph2b of tile -1)
#pragma unroll
  for (int g = 0; g < 2; ++g) {
    b0A[g][0] = LDB(0, 0, g, 0);
    b0A[g][1] = LDB(0, 0, g, 1);
  }
#pragma unroll
  for (int f = 0; f < 2; ++f) {
    a0[f][0] = LDA(0, 0, f, 0);
    a0[f][1] = LDA(0, 0, f, 1);
  }

#define TILEBODY(T, BC, BN_)                                                   \
  {                                                                            \
    const int bsel = (T) & 1;                                                  \
    /* ph0: reads a0[2,3](T) + b1(T); MFMA (M0,N0)=a0*BC (f01 first) */        \
    a0[2][0] = LDA(bsel, 0, 2, 0); a0[2][1] = LDA(bsel, 0, 2, 1);              \
    a0[3][0] = LDA(bsel, 0, 3, 0); a0[3][1] = LDA(bsel, 0, 3, 1);              \
    b1[0][0] = LDB(bsel, 1, 0, 0); b1[0][1] = LDB(bsel, 1, 0, 1);              \
    b1[1][0] = LDB(bsel, 1, 1, 0); b1[1][1] = LDB(bsel, 1, 1, 1);              \
    __builtin_amdgcn_s_setprio(1);                                             \
    _Pragma("unroll") for (int f = 0; f < 4; ++f)                              \
        _Pragma("unroll") for (int g = 0; g < 2; ++g) {                        \
      acc[f][g] = MFMA(a0[f][0], BC[g][0], acc[f][g]);                         \
      acc[f][g] = MFMA(a0[f][1], BC[g][1], acc[f][g]);                         \
    }                                                                          \
    __builtin_amdgcn_s_setprio(0);                                             \
    _Pragma("unroll") for (int i = 0; i < 8; ++i) { SG(0x100, 1); SG(0x8, 2); }\
    /* ph1: reads a1(T); MFMA (M0,N1)=a0*b1 */                                 \
    _Pragma("unroll") for (int f = 0; f < 4; ++f) {                            \
      a1[f][0] = LDA(bsel, 1, f, 0); a1[f][1] = LDA(bsel, 1, f, 1);            \
    }                                                                          \
    __builtin_amdgcn_s_setprio(1);                                             \
    _Pragma("unroll") for (int f = 0; f < 4; ++f)                              \
        _Pragma("unroll") for (int g = 0; g < 2; ++g) {                        \
      acc[f][2 + g] = MFMA(a0[f][0], b1[g][0], acc[f][2 + g]);                 \
      acc[f][2 + g] = MFMA(a0[f][1], b1[g][1], acc[f][2 + g]);                 \
    }                                                                          \
    __builtin_amdgcn_s_setprio(0);                                             \
    _Pragma("unroll") for (int i = 0; i < 8; ++i) { SG(0x100, 1); SG(0x8, 2); }\
    BAR(); /* #1: B-region of buf(T) free */                                   \
    /* ph2a: stage B(T+2); MFMA (M1,N1) f=0,1; gate */                         \
    STAGE2((T) + 2, 2, (T) + 2 < NT)                                           \
    STAGE2((T) + 2, 3, (T) + 2 < NT)                                           \
    __builtin_amdgcn_s_setprio(1);                                             \
    _Pragma("unroll") for (int f = 0; f < 2; ++f)                              \
        _Pragma("unroll") for (int g = 0; g < 2; ++g) {                        \
      acc[4 + f][2 + g] = MFMA(a1[f][0], b1[g][0], acc[4 + f][2 + g]);         \
      acc[4 + f][2 + g] = MFMA(a1[f][1], b1[g][1], acc[4 + f][2 + g]);         \
    }                                                                          \
    __builtin_amdgcn_s_setprio(0);                                             \
    SG(0x10, 4); SG(0x8, 8);                                                   \
    if ((T) + 2 < NT) {                                                        \
      asm volatile("s_waitcnt vmcnt(4)" ::: "memory");                         \
    } else {                                                                   \
      asm volatile("s_waitcnt vmcnt(0)" ::: "memory");                         \
    }                                                                          \
    BAR(); /* #2: tile T+1 data visible to all waves */                        \
    /* ph2b: reads b0(T+1)->BN_ + a0[0,1](T+1); MFMA (M1,N1) f=2,3 */          \
    if ((T) + 1 < NT) {                                                        \
      BN_[0][0] = LDB(bsel ^ 1, 0, 0, 0); BN_[0][1] = LDB(bsel ^ 1, 0, 0, 1);  \
      BN_[1][0] = LDB(bsel ^ 1, 0, 1, 0); BN_[1][1] = LDB(bsel ^ 1, 0, 1, 1);  \
      a0[0][0] = LDA(bsel ^ 1, 0, 0, 0); a0[0][1] = LDA(bsel ^ 1, 0, 0, 1);    \
      a0[1][0] = LDA(bsel ^ 1, 0, 1, 0); a0[1][1] = LDA(bsel ^ 1, 0, 1, 1);    \
    }                                                                          \
    __builtin_amdgcn_s_setprio(1);                                             \
    _Pragma("unroll") for (int f = 2; f < 4; ++f)                              \
        _Pragma("unroll") for (int g = 0; g < 2; ++g) {                        \
      acc[4 + f][2 + g] = MFMA(a1[f][0], b1[g][0], acc[4 + f][2 + g]);         \
      acc[4 + f][2 + g] = MFMA(a1[f][1], b1[g][1], acc[4 + f][2 + g]);         \
    }                                                                          \
    __builtin_amdgcn_s_setprio(0);                                             \
    _Pragma("unroll") for (int i = 0; i < 8; ++i) { SG(0x100, 1); SG(0x8, 1); }\
    /* ph3: stage A(T+2); MFMA (M1,N0)=a1*BC (pure, no reads) */               \
    STAGE2((T) + 2, 0, (T) + 2 < NT)                                           \
    STAGE2((T) + 2, 1, (T) + 2 < NT)                                           \
    __builtin_amdgcn_s_setprio(1);                                             \
    _Pragma("unroll") for (int f = 0; f < 4; ++f)                              \
        _Pragma("unroll") for (int g = 0; g < 2; ++g) {                        \
      acc[4 + f][g] = MFMA(a1[f][0], BC[g][0], acc[4 + f][g]);                 \
      acc[4 + f][g] = MFMA(a1[f][1], BC[g][1], acc[4 + f][g]);                 \
    }                                                                          \
    __builtin_amdgcn_s_setprio(0);                                             \
    SG(0x10, 4); SG(0x8, 16);                                                  \
  }

  for (int t = 0; t < NT; t += 2) {
    TILEBODY(t, b0A, b0B)
    if (t + 1 < NT) {
      TILEBODY(t + 1, b0B, b0A)
    }
  }

  // ---- epilogue: bias + f32 store (C/D: col = lane&15, row = (lane>>4)*4+e) ----
  const int colL = lane & 15;
  const int rowG = lane >> 4;
#pragma unroll
  for (int nj = 0; nj < 4; ++nj) {
    const int n = n0 + wc * 64 + nj * 16 + colL;
    const float bv = bias[n];
#pragma unroll
    for (int mi = 0; mi < 8; ++mi) {
      const int mb = m0 + wr * 128 + mi * 16 + rowG * 4;
#pragma unroll
      for (int e = 0; e < 4; ++e)
        out[(size_t)(mb + e) * OUT_F + n] = acc[mi][nj][e] + bv;
    }
  }
#undef TILEBODY
#undef STAGE2
#undef LDA
#undef LDB
#undef MFMA
#undef SG
#undef BAR
}

extern "C" void kernel_launch(void* const* d_in, const int* in_sizes, int n_in,
                              void* d_out, int out_size, void* d_ws, size_t ws_size,
                              hipStream_t stream) {
  (void)in_sizes; (void)n_in; (void)out_size; (void)ws_size;
  const float* x     = (const float*)d_in[0];
  const float* amax  = (const float*)d_in[1];
  const float* bias  = (const float*)d_in[2];
  const float* ldw   = (const float*)d_in[3];
  const float* luw   = (const float*)d_in[4];
  const float* alpha = (const float*)d_in[5];
  const int*   q     = (const int*)d_in[6];
  float* out = (float*)d_out;

  unsigned short* Ap = (unsigned short*)d_ws;                 // [NTOK][KP] bf16
  unsigned short* Bp = Ap + (size_t)NTOK * KP;                // [OUT_F][KP] bf16

  k_prep_a<<<NTOK / 4, 256, 0, stream>>>(x, ldw, Ap);
  k_prep_b<<<OUT_F, 256, 0, stream>>>(q, amax, luw, alpha, Bp);
  k_gemm<<<512, 512, 0, stream>>>(Ap, Bp, bias, out);
}

// Round 11
// 359.700 us; speedup vs baseline: 12.4702x; 1.1401x over previous
//
#include <hip/hip_runtime.h>

#define IN_F 4096
#define OUT_F 4096
#define RANK 16
#define NTOK 8192
#define KP 4160            // IN_F + 16 lora cols + 48 zero pad = 65 * 64
#define BK 64
#define NT (KP / BK)       // 65
#define BM 256
#define BN 256

typedef __bf16 bf16x8 __attribute__((ext_vector_type(8)));
typedef float f32x4 __attribute__((ext_vector_type(4)));

__device__ __forceinline__ unsigned short f2bf(float f) {
  unsigned int u = __float_as_uint(f);
  u += 0x7fffu + ((u >> 16) & 1u);   // round-to-nearest-even
  return (unsigned short)(u >> 16);
}

__device__ __forceinline__ void async_ld16(const void* g, void* l) {
  __builtin_amdgcn_global_load_lds(
      (const __attribute__((address_space(1))) unsigned int*)g,
      (__attribute__((address_space(3))) unsigned int*)l, 16, 0, 0);
}

__device__ const float NF4_TAB[16] = {
    -1.0f, -0.6961928009986877f, -0.5250730514526367f, -0.39491748809814453f,
    -0.28444138169288635f, -0.18477343022823334f, -0.09105003625154495f, 0.0f,
    0.07958029955625534f, 0.16093020141124725f, 0.24611230194568634f,
    0.33791524171829224f, 0.44070982933044434f, 0.5626170039176941f,
    0.7229568362236023f, 1.0f};

// ---------------- K1: x -> bf16 A', fused lora_down t = x @ Ld^T ----------------
// Wave-exclusive rows: block = 4 waves x 4 rows = 16 rows; x read ONCE per row
// (no cross-wave redundancy), bf16 convert+store same pass, per-lane partial
// dots for all 16 ranks, butterfly reduce (no LDS, no syncthreads).
__global__ __launch_bounds__(256) void k_prep_a(
    const float* __restrict__ x, const float* __restrict__ ldw,
    unsigned short* __restrict__ Ap) {
  const int tid = threadIdx.x;
  const int lane = tid & 63;
  const int w = tid >> 6;
  const int m0 = blockIdx.x * 16 + w * 4;   // this wave's 4 rows

  float dot[4][16];
#pragma unroll
  for (int i = 0; i < 4; ++i)
#pragma unroll
    for (int r = 0; r < 16; ++r) dot[i][r] = 0.f;

  for (int c = 0; c < 16; ++c) {
    const int k0 = (c * 64 + lane) * 4;
    float4 xv[4];
#pragma unroll
    for (int i = 0; i < 4; ++i) {
      xv[i] = *(const float4*)&x[(size_t)(m0 + i) * IN_F + k0];
      ushort4 s;
      s.x = f2bf(xv[i].x); s.y = f2bf(xv[i].y);
      s.z = f2bf(xv[i].z); s.w = f2bf(xv[i].w);
      *(ushort4*)&Ap[(size_t)(m0 + i) * KP + k0] = s;
    }
#pragma unroll
    for (int r = 0; r < 16; ++r) {
      float4 lv = *(const float4*)&ldw[(size_t)r * IN_F + k0];
#pragma unroll
      for (int i = 0; i < 4; ++i)
        dot[i][r] += xv[i].x * lv.x + xv[i].y * lv.y + xv[i].z * lv.z +
                     xv[i].w * lv.w;
    }
  }
  // butterfly reduce each of the 64 partials across the wave
#pragma unroll
  for (int i = 0; i < 4; ++i)
#pragma unroll
    for (int r = 0; r < 16; ++r) {
      float v = dot[i][r];
#pragma unroll
      for (int mm = 1; mm < 64; mm <<= 1) v += __shfl_xor(v, mm, 64);
      dot[i][r] = v;
    }
  // lanes 0..15: lora cols; lanes 16..63: zero pad (cols 4112..4159)
#pragma unroll
  for (int i = 0; i < 4; ++i) {
    unsigned short val = 0;
    if (lane < 16) {
      float dv;
      switch (lane) {   // static-index extract (rule 20)
        case 0: dv = dot[i][0]; break;   case 1: dv = dot[i][1]; break;
        case 2: dv = dot[i][2]; break;   case 3: dv = dot[i][3]; break;
        case 4: dv = dot[i][4]; break;   case 5: dv = dot[i][5]; break;
        case 6: dv = dot[i][6]; break;   case 7: dv = dot[i][7]; break;
        case 8: dv = dot[i][8]; break;   case 9: dv = dot[i][9]; break;
        case 10: dv = dot[i][10]; break; case 11: dv = dot[i][11]; break;
        case 12: dv = dot[i][12]; break; case 13: dv = dot[i][13]; break;
        case 14: dv = dot[i][14]; break; default: dv = dot[i][15]; break;
      }
      val = f2bf(dv);
    }
    Ap[(size_t)(m0 + i) * KP + IN_F + lane] = val;
  }
}

// ---------------- K2: NF4 dequant -> bf16 B', append Lu*(alpha/r) ----------------
__global__ __launch_bounds__(256) void k_prep_b(
    const int* __restrict__ q, const float* __restrict__ amax,
    const float* __restrict__ luw, const float* __restrict__ alpha,
    unsigned short* __restrict__ Bp) {
  __shared__ float tab[16];
  const int tid = threadIdx.x;
  const int n = blockIdx.x;
  if (tid < 16) tab[tid] = NF4_TAB[tid];
  __syncthreads();
#pragma unroll
  for (int c = 0; c < 4; ++c) {
    const int k0 = (tid + 256 * c) * 4;
    int4 qv = *(const int4*)&q[(size_t)n * IN_F + k0];
    float am = amax[n * (IN_F / 64) + (k0 >> 6)];
    ushort4 s;
    s.x = f2bf(tab[qv.x] * am);
    s.y = f2bf(tab[qv.y] * am);
    s.z = f2bf(tab[qv.z] * am);
    s.w = f2bf(tab[qv.w] * am);
    *(ushort4*)&Bp[(size_t)n * KP + k0] = s;
  }
  if (tid < RANK) {
    float sc = alpha[0] * (1.0f / RANK);
    Bp[(size_t)n * KP + IN_F + tid] = f2bf(luw[n * RANK + tid] * sc);
  } else if (tid < 64) {
    Bp[(size_t)n * KP + IN_F + tid] = 0;
  }
}

// ---------------- K3: 256x256 bf16 GEMM, SGB-interleaved DS||MFMA (R8 best) ----
// Quadrant order ph0 (M0,N0)=a0*b0, ph1 (M0,N1)=a0*b1, ph2 (M1,N1)=a1*b1,
// ph3 (M1,N0)=a1*b0. Reads one phase ahead; stages B(t+2)@ph2, A(t+2)@ph3;
// ONE counted vmcnt(4) per tile at end-ph2; 2 barriers/tile;
// sched_group_barrier interleaves DS_READ with MFMA inside phases.
__global__ __launch_bounds__(512, 1) void k_gemm(
    const unsigned short* __restrict__ Ap, const unsigned short* __restrict__ Bp,
    const float* __restrict__ bias, float* __restrict__ out) {
  __shared__ unsigned short lds[65536];  // 128 KiB
  const int tid = threadIdx.x;
  const int lane = tid & 63;
  const int w = tid >> 6;
  const int wr = w >> 2;       // 0..1
  const int wc = w & 3;        // 0..3

  // T1: XCD swizzle, 1-D grid of 512 (divisible by 8)
  const int flat = blockIdx.x;
  const int swz = (flat & 7) * 64 + (flat >> 3);
  const int m0 = (swz >> 4) * BM;
  const int n0 = (swz & 15) * BN;

  const int srow = lane >> 3;
  const int scol = (((lane & 7) ^ srow) << 3);
  const unsigned short* gA = Ap + (size_t)(m0 + (w << 4) + srow) * KP + scol;
  const unsigned short* gB = Bp + (size_t)(n0 + (w << 4) + srow) * KP + scol;
  unsigned short* const ldsw = lds + (w << 10);

  const int rdoff = ((lane & 15) << 6) + (((lane >> 4) ^ (lane & 7)) << 3);

#define STAGE2(tt, ht, cond)                                                   \
  if (cond) {                                                                  \
    const unsigned short* s_ =                                                 \
        ((ht) < 2 ? gA + (size_t)((ht) << 7) * KP                              \
                  : gB + (size_t)(((ht)-2) << 7) * KP) + (size_t)(tt)*BK;      \
    unsigned short* d_ = ldsw + ((((tt)&1) << 15) + ((ht) << 13));             \
    async_ld16(s_, d_);                                                        \
    async_ld16(s_ + (size_t)8 * KP, d_ + 512);                                 \
  }

#define LDA(bsel, mh, f, kc)                                                   \
  (*(const bf16x8*)&lds[((bsel) << 15) + (wr << 13) +                          \
                        (((mh)*64 + (f)*16) << 6) + (((kc) << 5) ^ rdoff)])
#define LDB(bsel, nh, g, kc)                                                   \
  (*(const bf16x8*)&lds[((bsel) << 15) + ((2 + (wc >> 1)) << 13) +             \
                        ((((wc & 1) * 64) + (nh)*32 + (g)*16) << 6) +          \
                        (((kc) << 5) ^ rdoff)])

#define MFMA(a, b, c) __builtin_amdgcn_mfma_f32_16x16x32_bf16((a), (b), (c), 0, 0, 0)
// sched_group_barrier masks: MFMA=0x8, VMEM=0x10, DS_READ=0x100
#define SG(mask, n) __builtin_amdgcn_sched_group_barrier((mask), (n), 0)

  // ---- prologue: B(0),A(0),B(1),A(1) FIFO; land tile0; first frags ----
  STAGE2(0, 2, true) STAGE2(0, 3, true) STAGE2(0, 0, true) STAGE2(0, 1, true)
  STAGE2(1, 2, true) STAGE2(1, 3, true) STAGE2(1, 0, true) STAGE2(1, 1, true)
  asm volatile("s_waitcnt vmcnt(8)" ::: "memory");   // tile0 landed
  __builtin_amdgcn_s_barrier();

  f32x4 acc[8][4] = {};
  bf16x8 a0[4][2], a1[4][2], b0[2][2], b1[2][2];

  // initial fragments for ph0(0): b0(0), a0(0)  (plays role of ph3 of tile -1)
#pragma unroll
  for (int g = 0; g < 2; ++g) {
    b0[g][0] = LDB(0, 0, g, 0);
    b0[g][1] = LDB(0, 0, g, 1);
  }
#pragma unroll
  for (int f = 0; f < 4; ++f) {
    a0[f][0] = LDA(0, 0, f, 0);
    a0[f][1] = LDA(0, 0, f, 1);
  }

#pragma unroll 2
  for (int t = 0; t < NT; ++t) {
    const int bsel = t & 1;
    // ---- phase 0: MFMA (M0,N0)=a0*b0; prefetch b1(t)[4] + a1(t) half[4] ----
#pragma unroll
    for (int g = 0; g < 2; ++g) {
      b1[g][0] = LDB(bsel, 1, g, 0);
      b1[g][1] = LDB(bsel, 1, g, 1);
    }
#pragma unroll
    for (int f = 0; f < 2; ++f) {
      a1[f][0] = LDA(bsel, 1, f, 0);
      a1[f][1] = LDA(bsel, 1, f, 1);
    }
#pragma unroll
    for (int f = 0; f < 4; ++f)
#pragma unroll
      for (int g = 0; g < 2; ++g) {
        acc[f][g] = MFMA(a0[f][0], b0[g][0], acc[f][g]);
        acc[f][g] = MFMA(a0[f][1], b0[g][1], acc[f][g]);
      }
#pragma unroll
    for (int i = 0; i < 8; ++i) { SG(0x100, 1); SG(0x8, 2); }
    // ---- phase 1: MFMA (M0,N1)=a0*b1; prefetch a1(t) second half[4] ----
#pragma unroll
    for (int f = 2; f < 4; ++f) {
      a1[f][0] = LDA(bsel, 1, f, 0);
      a1[f][1] = LDA(bsel, 1, f, 1);
    }
#pragma unroll
    for (int f = 0; f < 4; ++f)
#pragma unroll
      for (int g = 0; g < 2; ++g) {
        acc[f][2 + g] = MFMA(a0[f][0], b1[g][0], acc[f][2 + g]);
        acc[f][2 + g] = MFMA(a0[f][1], b1[g][1], acc[f][2 + g]);
      }
#pragma unroll
    for (int i = 0; i < 4; ++i) { SG(0x100, 1); SG(0x8, 4); }
    __builtin_amdgcn_s_barrier();                    // barrier #1
    // ---- phase 2: MFMA (M1,N1)=a1*b1; stage B(t+2); vmcnt retires t+1 ----
    STAGE2(t + 2, 2, t + 2 < NT)
    STAGE2(t + 2, 3, t + 2 < NT)
#pragma unroll
    for (int f = 0; f < 4; ++f)
#pragma unroll
      for (int g = 0; g < 2; ++g) {
        acc[4 + f][2 + g] = MFMA(a1[f][0], b1[g][0], acc[4 + f][2 + g]);
        acc[4 + f][2 + g] = MFMA(a1[f][1], b1[g][1], acc[4 + f][2 + g]);
      }
    SG(0x10, 4); SG(0x8, 16);
    if (t < NT - 2) {
      asm volatile("s_waitcnt vmcnt(4)" ::: "memory");  // keep B(t+2) in flight
    } else {
      asm volatile("s_waitcnt vmcnt(0)" ::: "memory");  // pipeline ending
    }
    __builtin_amdgcn_s_barrier();                    // barrier #2
    // ---- phase 3: MFMA (M1,N0)=a1*b0; stage A(t+2); prefetch a0(t+1)[8]
    //      interleaved; b0(t+1)[4] after (WAR on b0) ----
    STAGE2(t + 2, 0, t + 2 < NT)
    STAGE2(t + 2, 1, t + 2 < NT)
    if (t + 1 < NT) {
#pragma unroll
      for (int f = 0; f < 4; ++f) {
        a0[f][0] = LDA(bsel ^ 1, 0, f, 0);
        a0[f][1] = LDA(bsel ^ 1, 0, f, 1);
      }
    }
#pragma unroll
    for (int f = 0; f < 4; ++f)
#pragma unroll
      for (int g = 0; g < 2; ++g) {
        acc[4 + f][g] = MFMA(a1[f][0], b0[g][0], acc[4 + f][g]);
        acc[4 + f][g] = MFMA(a1[f][1], b0[g][1], acc[4 + f][g]);
      }
    if (t + 1 < NT) {
#pragma unroll
      for (int g = 0; g < 2; ++g) {
        b0[g][0] = LDB(bsel ^ 1, 0, g, 0);
        b0[g][1] = LDB(bsel ^ 1, 0, g, 1);
      }
    }
    SG(0x10, 4);
#pragma unroll
    for (int i = 0; i < 8; ++i) { SG(0x100, 1); SG(0x8, 2); }
    SG(0x100, 4);
  }

  // ---- epilogue: bias + f32 store (C/D: col = lane&15, row = (lane>>4)*4+e) ----
  const int colL = lane & 15;
  const int rowG = lane >> 4;
#pragma unroll
  for (int nj = 0; nj < 4; ++nj) {
    const int n = n0 + wc * 64 + nj * 16 + colL;
    const float bv = bias[n];
#pragma unroll
    for (int mi = 0; mi < 8; ++mi) {
      const int mb = m0 + wr * 128 + mi * 16 + rowG * 4;
#pragma unroll
      for (int e = 0; e < 4; ++e)
        out[(size_t)(mb + e) * OUT_F + n] = acc[mi][nj][e] + bv;
    }
  }
#undef STAGE2
#undef LDA
#undef LDB
#undef MFMA
#undef SG
}

extern "C" void kernel_launch(void* const* d_in, const int* in_sizes, int n_in,
                              void* d_out, int out_size, void* d_ws, size_t ws_size,
                              hipStream_t stream) {
  (void)in_sizes; (void)n_in; (void)out_size; (void)ws_size;
  const float* x     = (const float*)d_in[0];
  const float* amax  = (const float*)d_in[1];
  const float* bias  = (const float*)d_in[2];
  const float* ldw   = (const float*)d_in[3];
  const float* luw   = (const float*)d_in[4];
  const float* alpha = (const float*)d_in[5];
  const int*   q     = (const int*)d_in[6];
  float* out = (float*)d_out;

  unsigned short* Ap = (unsigned short*)d_ws;                 // [NTOK][KP] bf16
  unsigned short* Bp = Ap + (size_t)NTOK * KP;                // [OUT_F][KP] bf16

  k_prep_a<<<NTOK / 16, 256, 0, stream>>>(x, ldw, Ap);
  k_prep_b<<<OUT_F, 256, 0, stream>>>(q, amax, luw, alpha, Bp);
  k_gemm<<<512, 512, 0, stream>>>(Ap, Bp, bias, out);
}

// Round 12
// 316.069 us; speedup vs baseline: 14.1917x; 1.1380x over previous
//
#include <hip/hip_runtime.h>

#define IN_F 4096
#define OUT_F 4096
#define RANK 16
#define NTOK 8192
#define KP 4160            // IN_F + 16 lora cols + 48 zero pad = 65 * 64
#define BK 64
#define NT (KP / BK)       // 65
#define BM 256
#define BN 256

typedef __bf16 bf16x8 __attribute__((ext_vector_type(8)));
typedef float f32x4 __attribute__((ext_vector_type(4)));

__device__ __forceinline__ unsigned short f2bf(float f) {
  unsigned int u = __float_as_uint(f);
  u += 0x7fffu + ((u >> 16) & 1u);   // round-to-nearest-even
  return (unsigned short)(u >> 16);
}

__device__ __forceinline__ void async_ld16(const void* g, void* l) {
  __builtin_amdgcn_global_load_lds(
      (const __attribute__((address_space(1))) unsigned int*)g,
      (__attribute__((address_space(3))) unsigned int*)l, 16, 0, 0);
}

__device__ const float NF4_TAB[16] = {
    -1.0f, -0.6961928009986877f, -0.5250730514526367f, -0.39491748809814453f,
    -0.28444138169288635f, -0.18477343022823334f, -0.09105003625154495f, 0.0f,
    0.07958029955625534f, 0.16093020141124725f, 0.24611230194568634f,
    0.33791524171829224f, 0.44070982933044434f, 0.5626170039176941f,
    0.7229568362236023f, 1.0f};

// ---------------- K1: merged prep ----------------
// blocks [0, NTOK/4): prep_a — x -> bf16 A' + fused lora_down (R8-proven form:
//   4 waves, wave w computes ranks 4w..4w+3 over 4 rows; 16 partials/lane,
//   96 shuffles; wave i writes row i's bf16 conversion).
// blocks [NTOK/4, NTOK/4+OUT_F): prep_b — NF4 dequant -> bf16 B' + Lu cols.
// Merged so the VALU/L2-bound prep_a overlaps the HBM-bound prep_b instead of
// serializing, and one launch is saved.
__global__ __launch_bounds__(256) void k_prep(
    const float* __restrict__ x, const float* __restrict__ ldw,
    const int* __restrict__ q, const float* __restrict__ amax,
    const float* __restrict__ luw, const float* __restrict__ alpha,
    unsigned short* __restrict__ Ap, unsigned short* __restrict__ Bp) {
  const int tid = threadIdx.x;
  if ((int)blockIdx.x < NTOK / 4) {
    // ---------------- prep_a ----------------
    const int lane = tid & 63;
    const int w = tid >> 6;
    const int m0 = blockIdx.x * 4;

    float acc[4][4];
#pragma unroll
    for (int i = 0; i < 4; ++i)
#pragma unroll
      for (int rl = 0; rl < 4; ++rl) acc[i][rl] = 0.f;

    for (int c = 0; c < 16; ++c) {
      const int k0 = (c * 64 + lane) * 4;
      float4 xv[4];
#pragma unroll
      for (int i = 0; i < 4; ++i) {
        xv[i] = *(const float4*)&x[(size_t)(m0 + i) * IN_F + k0];
        if (w == i) {  // wave i writes row i's bf16 conversion (balanced)
          ushort4 s;
          s.x = f2bf(xv[i].x); s.y = f2bf(xv[i].y);
          s.z = f2bf(xv[i].z); s.w = f2bf(xv[i].w);
          *(ushort4*)&Ap[(size_t)(m0 + i) * KP + k0] = s;
        }
      }
#pragma unroll
      for (int rl = 0; rl < 4; ++rl) {
        float4 lv = *(const float4*)&ldw[(size_t)(w * 4 + rl) * IN_F + k0];
#pragma unroll
        for (int i = 0; i < 4; ++i)
          acc[i][rl] += xv[i].x * lv.x + xv[i].y * lv.y + xv[i].z * lv.z +
                        xv[i].w * lv.w;
      }
    }
#pragma unroll
    for (int i = 0; i < 4; ++i)
#pragma unroll
      for (int rl = 0; rl < 4; ++rl) {
        float v = acc[i][rl];
#pragma unroll
        for (int m = 1; m < 64; m <<= 1) v += __shfl_xor(v, m, 64);
        acc[i][rl] = v;
      }
    __shared__ float red[4][16];
    if (lane == 0) {
#pragma unroll
      for (int i = 0; i < 4; ++i)
#pragma unroll
        for (int rl = 0; rl < 4; ++rl) red[i][w * 4 + rl] = acc[i][rl];
    }
    __syncthreads();
    if (tid < 64) {  // lora columns 4096..4111
      Ap[(size_t)(m0 + (tid >> 4)) * KP + IN_F + (tid & 15)] =
          f2bf(red[tid >> 4][tid & 15]);
    } else {  // zero pad cols 4112..4159 : 4 rows x 48 cols = 192 elems
      const int t2 = tid - 64;
      if (t2 < 192)
        Ap[(size_t)(m0 + t2 / 48) * KP + IN_F + 16 + (t2 % 48)] = 0;
    }
  } else {
    // ---------------- prep_b ----------------
    __shared__ float tab[16];
    const int n = blockIdx.x - NTOK / 4;
    if (tid < 16) tab[tid] = NF4_TAB[tid];
    __syncthreads();
#pragma unroll
    for (int c = 0; c < 4; ++c) {
      const int k0 = (tid + 256 * c) * 4;
      int4 qv = *(const int4*)&q[(size_t)n * IN_F + k0];
      float am = amax[n * (IN_F / 64) + (k0 >> 6)];
      ushort4 s;
      s.x = f2bf(tab[qv.x] * am);
      s.y = f2bf(tab[qv.y] * am);
      s.z = f2bf(tab[qv.z] * am);
      s.w = f2bf(tab[qv.w] * am);
      *(ushort4*)&Bp[(size_t)n * KP + k0] = s;
    }
    if (tid < RANK) {
      float sc = alpha[0] * (1.0f / RANK);
      Bp[(size_t)n * KP + IN_F + tid] = f2bf(luw[n * RANK + tid] * sc);
    } else if (tid < 64) {  // zero pad cols 4112..4159
      Bp[(size_t)n * KP + IN_F + tid] = 0;
    }
  }
}

// ---------------- K3: 256x256 bf16 GEMM, SGB-interleaved DS||MFMA (R11 best) ---
// Quadrant order ph0 (M0,N0)=a0*b0, ph1 (M0,N1)=a0*b1, ph2 (M1,N1)=a1*b1,
// ph3 (M1,N0)=a1*b0. Reads one phase ahead; stages B(t+2)@ph2, A(t+2)@ph3;
// ONE counted vmcnt(4) per tile at end-ph2; 2 barriers/tile;
// sched_group_barrier interleaves DS_READ with MFMA inside phases.
__global__ __launch_bounds__(512, 1) void k_gemm(
    const unsigned short* __restrict__ Ap, const unsigned short* __restrict__ Bp,
    const float* __restrict__ bias, float* __restrict__ out) {
  __shared__ unsigned short lds[65536];  // 128 KiB
  const int tid = threadIdx.x;
  const int lane = tid & 63;
  const int w = tid >> 6;
  const int wr = w >> 2;       // 0..1
  const int wc = w & 3;        // 0..3

  // T1: XCD swizzle, 1-D grid of 512 (divisible by 8)
  const int flat = blockIdx.x;
  const int swz = (flat & 7) * 64 + (flat >> 3);
  const int m0 = (swz >> 4) * BM;
  const int n0 = (swz & 15) * BN;

  const int srow = lane >> 3;
  const int scol = (((lane & 7) ^ srow) << 3);
  const unsigned short* gA = Ap + (size_t)(m0 + (w << 4) + srow) * KP + scol;
  const unsigned short* gB = Bp + (size_t)(n0 + (w << 4) + srow) * KP + scol;
  unsigned short* const ldsw = lds + (w << 10);

  const int rdoff = ((lane & 15) << 6) + (((lane >> 4) ^ (lane & 7)) << 3);

#define STAGE2(tt, ht, cond)                                                   \
  if (cond) {                                                                  \
    const unsigned short* s_ =                                                 \
        ((ht) < 2 ? gA + (size_t)((ht) << 7) * KP                              \
                  : gB + (size_t)(((ht)-2) << 7) * KP) + (size_t)(tt)*BK;      \
    unsigned short* d_ = ldsw + ((((tt)&1) << 15) + ((ht) << 13));             \
    async_ld16(s_, d_);                                                        \
    async_ld16(s_ + (size_t)8 * KP, d_ + 512);                                 \
  }

#define LDA(bsel, mh, f, kc)                                                   \
  (*(const bf16x8*)&lds[((bsel) << 15) + (wr << 13) +                          \
                        (((mh)*64 + (f)*16) << 6) + (((kc) << 5) ^ rdoff)])
#define LDB(bsel, nh, g, kc)                                                   \
  (*(const bf16x8*)&lds[((bsel) << 15) + ((2 + (wc >> 1)) << 13) +             \
                        ((((wc & 1) * 64) + (nh)*32 + (g)*16) << 6) +          \
                        (((kc) << 5) ^ rdoff)])

#define MFMA(a, b, c) __builtin_amdgcn_mfma_f32_16x16x32_bf16((a), (b), (c), 0, 0, 0)
// sched_group_barrier masks: MFMA=0x8, VMEM=0x10, DS_READ=0x100
#define SG(mask, n) __builtin_amdgcn_sched_group_barrier((mask), (n), 0)

  // ---- prologue: B(0),A(0),B(1),A(1) FIFO; land tile0; first frags ----
  STAGE2(0, 2, true) STAGE2(0, 3, true) STAGE2(0, 0, true) STAGE2(0, 1, true)
  STAGE2(1, 2, true) STAGE2(1, 3, true) STAGE2(1, 0, true) STAGE2(1, 1, true)
  asm volatile("s_waitcnt vmcnt(8)" ::: "memory");   // tile0 landed
  __builtin_amdgcn_s_barrier();

  f32x4 acc[8][4] = {};
  bf16x8 a0[4][2], a1[4][2], b0[2][2], b1[2][2];

  // initial fragments for ph0(0): b0(0), a0(0)  (plays role of ph3 of tile -1)
#pragma unroll
  for (int g = 0; g < 2; ++g) {
    b0[g][0] = LDB(0, 0, g, 0);
    b0[g][1] = LDB(0, 0, g, 1);
  }
#pragma unroll
  for (int f = 0; f < 4; ++f) {
    a0[f][0] = LDA(0, 0, f, 0);
    a0[f][1] = LDA(0, 0, f, 1);
  }

#pragma unroll 2
  for (int t = 0; t < NT; ++t) {
    const int bsel = t & 1;
    // ---- phase 0: MFMA (M0,N0)=a0*b0; prefetch b1(t)[4] + a1(t) half[4] ----
#pragma unroll
    for (int g = 0; g < 2; ++g) {
      b1[g][0] = LDB(bsel, 1, g, 0);
      b1[g][1] = LDB(bsel, 1, g, 1);
    }
#pragma unroll
    for (int f = 0; f < 2; ++f) {
      a1[f][0] = LDA(bsel, 1, f, 0);
      a1[f][1] = LDA(bsel, 1, f, 1);
    }
#pragma unroll
    for (int f = 0; f < 4; ++f)
#pragma unroll
      for (int g = 0; g < 2; ++g) {
        acc[f][g] = MFMA(a0[f][0], b0[g][0], acc[f][g]);
        acc[f][g] = MFMA(a0[f][1], b0[g][1], acc[f][g]);
      }
#pragma unroll
    for (int i = 0; i < 8; ++i) { SG(0x100, 1); SG(0x8, 2); }
    // ---- phase 1: MFMA (M0,N1)=a0*b1; prefetch a1(t) second half[4] ----
#pragma unroll
    for (int f = 2; f < 4; ++f) {
      a1[f][0] = LDA(bsel, 1, f, 0);
      a1[f][1] = LDA(bsel, 1, f, 1);
    }
#pragma unroll
    for (int f = 0; f < 4; ++f)
#pragma unroll
      for (int g = 0; g < 2; ++g) {
        acc[f][2 + g] = MFMA(a0[f][0], b1[g][0], acc[f][2 + g]);
        acc[f][2 + g] = MFMA(a0[f][1], b1[g][1], acc[f][2 + g]);
      }
#pragma unroll
    for (int i = 0; i < 4; ++i) { SG(0x100, 1); SG(0x8, 4); }
    __builtin_amdgcn_s_barrier();                    // barrier #1
    // ---- phase 2: MFMA (M1,N1)=a1*b1; stage B(t+2); vmcnt retires t+1 ----
    STAGE2(t + 2, 2, t + 2 < NT)
    STAGE2(t + 2, 3, t + 2 < NT)
#pragma unroll
    for (int f = 0; f < 4; ++f)
#pragma unroll
      for (int g = 0; g < 2; ++g) {
        acc[4 + f][2 + g] = MFMA(a1[f][0], b1[g][0], acc[4 + f][2 + g]);
        acc[4 + f][2 + g] = MFMA(a1[f][1], b1[g][1], acc[4 + f][2 + g]);
      }
    SG(0x10, 4); SG(0x8, 16);
    if (t < NT - 2) {
      asm volatile("s_waitcnt vmcnt(4)" ::: "memory");  // keep B(t+2) in flight
    } else {
      asm volatile("s_waitcnt vmcnt(0)" ::: "memory");  // pipeline ending
    }
    __builtin_amdgcn_s_barrier();                    // barrier #2
    // ---- phase 3: MFMA (M1,N0)=a1*b0; stage A(t+2); prefetch a0(t+1)[8]
    //      interleaved; b0(t+1)[4] after (WAR on b0) ----
    STAGE2(t + 2, 0, t + 2 < NT)
    STAGE2(t + 2, 1, t + 2 < NT)
    if (t + 1 < NT) {
#pragma unroll
      for (int f = 0; f < 4; ++f) {
        a0[f][0] = LDA(bsel ^ 1, 0, f, 0);
        a0[f][1] = LDA(bsel ^ 1, 0, f, 1);
      }
    }
#pragma unroll
    for (int f = 0; f < 4; ++f)
#pragma unroll
      for (int g = 0; g < 2; ++g) {
        acc[4 + f][g] = MFMA(a1[f][0], b0[g][0], acc[4 + f][g]);
        acc[4 + f][g] = MFMA(a1[f][1], b0[g][1], acc[4 + f][g]);
      }
    if (t + 1 < NT) {
#pragma unroll
      for (int g = 0; g < 2; ++g) {
        b0[g][0] = LDB(bsel ^ 1, 0, g, 0);
        b0[g][1] = LDB(bsel ^ 1, 0, g, 1);
      }
    }
    SG(0x10, 4);
#pragma unroll
    for (int i = 0; i < 8; ++i) { SG(0x100, 1); SG(0x8, 2); }
    SG(0x100, 4);
  }

  // ---- epilogue: bias + f32 store (C/D: col = lane&15, row = (lane>>4)*4+e) ----
  const int colL = lane & 15;
  const int rowG = lane >> 4;
#pragma unroll
  for (int nj = 0; nj < 4; ++nj) {
    const int n = n0 + wc * 64 + nj * 16 + colL;
    const float bv = bias[n];
#pragma unroll
    for (int mi = 0; mi < 8; ++mi) {
      const int mb = m0 + wr * 128 + mi * 16 + rowG * 4;
#pragma unroll
      for (int e = 0; e < 4; ++e)
        out[(size_t)(mb + e) * OUT_F + n] = acc[mi][nj][e] + bv;
    }
  }
#undef STAGE2
#undef LDA
#undef LDB
#undef MFMA
#undef SG
}

extern "C" void kernel_launch(void* const* d_in, const int* in_sizes, int n_in,
                              void* d_out, int out_size, void* d_ws, size_t ws_size,
                              hipStream_t stream) {
  (void)in_sizes; (void)n_in; (void)out_size; (void)ws_size;
  const float* x     = (const float*)d_in[0];
  const float* amax  = (const float*)d_in[1];
  const float* bias  = (const float*)d_in[2];
  const float* ldw   = (const float*)d_in[3];
  const float* luw   = (const float*)d_in[4];
  const float* alpha = (const float*)d_in[5];
  const int*   q     = (const int*)d_in[6];
  float* out = (float*)d_out;

  unsigned short* Ap = (unsigned short*)d_ws;                 // [NTOK][KP] bf16
  unsigned short* Bp = Ap + (size_t)NTOK * KP;                // [OUT_F][KP] bf16

  k_prep<<<NTOK / 4 + OUT_F, 256, 0, stream>>>(x, ldw, q, amax, luw, alpha, Ap, Bp);
  k_gemm<<<512, 512, 0, stream>>>(Ap, Bp, bias, out);
}